// Round 1
// baseline (231.944 us; speedup 1.0000x reference)
//
#include <hip/hip_runtime.h>
#include <hip/hip_bf16.h>

#define NN 4096
#define IN_F 512
#define HALF 256
#define FF 64
#define ALPHA 0.2f
#define EPSV 1e-5f
#define CAP1 256
#define CAP2 1024

typedef unsigned long long u64;
typedef unsigned int u32;

__device__ __forceinline__ float lrelu(float x){ return x > 0.f ? x : ALPHA * x; }

// ---------------- Kernel 1: bit-pack adjacency rows ----------------
// packA[i*64 + w] bit b  <=>  adj[i, w*64+b] > 0
__global__ __launch_bounds__(256) void pack_kernel(const float* __restrict__ adj,
                                                   u64* __restrict__ packA) {
    int i = blockIdx.x;
    int tid = threadIdx.x;
    int wave = tid >> 6, lane = tid & 63;
    const float* row = adj + (size_t)i * NN;
    #pragma unroll
    for (int t = 0; t < NN / 256; ++t) {
        int col = t * 256 + tid;
        u64 m = __ballot(row[col] > 0.f);
        if (lane == 0) packA[(size_t)i * 64 + t * 4 + wave] = m;
    }
}

// ---------------- Kernel 2: Wh1/Wh2 GEMV + attention scalars ----------------
// block = 128 threads: wave0 -> (W1, left half of h), wave1 -> (W2, right half)
__global__ __launch_bounds__(128) void wh_kernel(const float* __restrict__ h,
                                                 const float* __restrict__ W1,
                                                 const float* __restrict__ W2,
                                                 const float* __restrict__ a,
                                                 float* __restrict__ Wh1,
                                                 float* __restrict__ Wh2,
                                                 float* __restrict__ s11,
                                                 float* __restrict__ s12,
                                                 float* __restrict__ s21,
                                                 float* __restrict__ s22) {
    int i = blockIdx.x;
    int tid = threadIdx.x;
    int wave = tid >> 6;          // 0: branch1, 1: branch2
    int f = tid & 63;
    const float* W = wave ? W2 : W1;
    const float* hrow = h + (size_t)i * IN_F + wave * HALF;
    float acc = 0.f;
    #pragma unroll 8
    for (int k = 0; k < HALF; ++k) acc += hrow[k] * W[k * FF + f];
    (wave ? Wh2 : Wh1)[(size_t)i * FF + f] = acc;
    float v1 = acc * a[f];
    float v2 = acc * a[64 + f];
    #pragma unroll
    for (int off = 32; off; off >>= 1) {
        v1 += __shfl_down(v1, off, 64);
        v2 += __shfl_down(v2, off, 64);
    }
    if (f == 0) {
        if (wave == 0) { s11[i] = v1; s12[i] = v2; }
        else           { s21[i] = v1; s22[i] = v2; }
    }
}

// ---------------- fused attention: shared helper ----------------
// masked softmax over a compacted (j, e) list, then weighted gather of Wh rows.
// cnt == 0 -> reference semantics give uniform attention over ALL j.
__device__ __forceinline__ void softmax_accum(int cnt, const int* __restrict__ nbr,
                                              float* __restrict__ ev,
                                              const float* __restrict__ Wh,
                                              float* __restrict__ outp,
                                              int tid, float* red, float* partial) {
    int wave = tid >> 6, lane = tid & 63;
    float Z;
    if (cnt > 0) {
        float m = -3.4e38f;
        for (int n = tid; n < cnt; n += 256) m = fmaxf(m, ev[n]);
        #pragma unroll
        for (int off = 32; off; off >>= 1) m = fmaxf(m, __shfl_down(m, off, 64));
        if (lane == 0) red[wave] = m;
        __syncthreads();
        m = fmaxf(fmaxf(red[0], red[1]), fmaxf(red[2], red[3]));
        __syncthreads();
        float s = 0.f;
        for (int n = tid; n < cnt; n += 256) {
            float p = __expf(ev[n] - m);
            ev[n] = p;
            s += p;
        }
        #pragma unroll
        for (int off = 32; off; off >>= 1) s += __shfl_down(s, off, 64);
        if (lane == 0) red[wave] = s;
        __syncthreads();
        Z = red[0] + red[1] + red[2] + red[3];
        __syncthreads();
    } else {
        Z = (float)NN;
    }
    int f = tid & 63, grp = tid >> 6;
    float acc = 0.f;
    if (cnt > 0) {
        for (int n = grp; n < cnt; n += 4) acc += ev[n] * Wh[(size_t)nbr[n] * FF + f];
    } else {
        for (int n = grp; n < NN; n += 4) acc += Wh[(size_t)n * FF + f];
    }
    partial[tid] = acc;
    __syncthreads();
    if (tid < 64)
        outp[tid] = (partial[tid] + partial[tid + 64] + partial[tid + 128] + partial[tid + 192]) / Z;
    __syncthreads();
}

// ---------------- Kernel 3: per-row fused attention (both hops) ----------------
__global__ __launch_bounds__(256) void attn_kernel(const u64* __restrict__ packA,
                                                   const float* __restrict__ Wh1,
                                                   const float* __restrict__ Wh2,
                                                   const float* __restrict__ s11,
                                                   const float* __restrict__ s12,
                                                   const float* __restrict__ s21,
                                                   const float* __restrict__ s22,
                                                   float* __restrict__ hp) {
    int i = blockIdx.x;
    int tid = threadIdx.x;
    int wave = tid >> 6, lane = tid & 63;

    __shared__ u32 mask2[128];
    __shared__ int cnt1, cnt2;
    __shared__ int   nbr1[CAP1];
    __shared__ float ev1[CAP1];
    __shared__ int   nbr2[CAP2];
    __shared__ float ev2[CAP2];
    __shared__ float red[4];
    __shared__ float partial[256];

    if (tid < 128) mask2[tid] = 0u;
    if (tid == 0) { cnt1 = 0; cnt2 = 0; }
    __syncthreads();

    float s11i = s11[i], s21i = s21[i];

    // --- hop-1 neighbor list from packed row i ---
    if (tid < 64) {
        u64 bits = packA[(size_t)i * 64 + tid];
        while (bits) {
            int b = __builtin_ctzll(bits);
            bits &= bits - 1;
            int j = (tid << 6) | b;
            int pos = atomicAdd(&cnt1, 1);
            if (pos < CAP1) {
                nbr1[pos] = j;
                ev1[pos] = lrelu(s11i + s12[j]);
            }
        }
    }
    __syncthreads();
    int c1 = min(cnt1, CAP1);

    // --- build 2-hop mask: OR of neighbor bit-rows ---
    for (int n = wave; n < c1; n += 4) {
        u64 bits = packA[(size_t)nbr1[n] * 64 + lane];
        atomicOr(&mask2[2 * lane],     (u32)bits);
        atomicOr(&mask2[2 * lane + 1], (u32)(bits >> 32));
    }
    __syncthreads();
    if (tid == 0) mask2[i >> 5] &= ~(1u << (i & 31));   // zero diagonal of adj2
    __syncthreads();

    // --- hop-1 softmax + gather -> hp[i, 0:64] ---
    softmax_accum(c1, nbr1, ev1, Wh1, hp + (size_t)i * 128, tid, red, partial);

    // --- hop-2 neighbor list from mask2 ---
    if (tid < 128) {
        u32 bits = mask2[tid];
        while (bits) {
            int b = __builtin_ctz(bits);
            bits &= bits - 1;
            int j = (tid << 5) | b;
            int pos = atomicAdd(&cnt2, 1);
            if (pos < CAP2) {
                nbr2[pos] = j;
                ev2[pos] = lrelu(s21i + s22[j]);
            }
        }
    }
    __syncthreads();
    int c2 = min(cnt2, CAP2);

    // --- hop-2 softmax + gather -> hp[i, 64:128] ---
    softmax_accum(c2, nbr2, ev2, Wh2, hp + (size_t)i * 128 + 64, tid, red, partial);
}

// ---------------- Kernel 4: column sums for batchnorm ----------------
__global__ __launch_bounds__(256) void stats_kernel(const float* __restrict__ hp,
                                                    float* __restrict__ colsum,
                                                    float* __restrict__ colsq) {
    __shared__ float ls[128], lq[128];
    int tid = threadIdx.x;
    if (tid < 128) { ls[tid] = 0.f; lq[tid] = 0.f; }
    __syncthreads();
    float s = 0.f, q = 0.f;
    for (size_t idx = (size_t)blockIdx.x * 256 + tid; idx < (size_t)NN * 128;
         idx += (size_t)gridDim.x * 256) {
        float v = hp[idx];
        s += v; q += v * v;
    }
    int c = tid & 127;
    atomicAdd(&ls[c], s);
    atomicAdd(&lq[c], q);
    __syncthreads();
    if (tid < 128) {
        atomicAdd(&colsum[tid], ls[tid]);
        atomicAdd(&colsq[tid], lq[tid]);
    }
}

// ---------------- Kernel 5: batchnorm + lrelu (in place on d_out) ----------------
__global__ __launch_bounds__(256) void norm_kernel(float* __restrict__ hp,
                                                   const float* __restrict__ colsum,
                                                   const float* __restrict__ colsq,
                                                   const float* __restrict__ gamma,
                                                   const float* __restrict__ beta) {
    size_t idx = (size_t)blockIdx.x * 256 + threadIdx.x;
    if (idx >= (size_t)NN * 128) return;
    int c = (int)(idx & 127);
    float mean = colsum[c] * (1.f / NN);
    float var = colsq[c] * (1.f / NN) - mean * mean;
    float inv = rsqrtf(var + EPSV);
    float v = (hp[idx] - mean) * inv * gamma[c] + beta[c];
    hp[idx] = lrelu(v);
}

extern "C" void kernel_launch(void* const* d_in, const int* in_sizes, int n_in,
                              void* d_out, int out_size, void* d_ws, size_t ws_size,
                              hipStream_t stream) {
    const float* h     = (const float*)d_in[0];
    const float* adj   = (const float*)d_in[1];
    const float* W1    = (const float*)d_in[2];
    const float* W2    = (const float*)d_in[3];
    const float* a     = (const float*)d_in[4];
    const float* gamma = (const float*)d_in[5];
    const float* beta  = (const float*)d_in[6];
    float* hp = (float*)d_out;   // [4096, 128] concat(h_prime1, h_prime2), then BN in place

    // workspace layout
    u64* packA  = (u64*)d_ws;                     // 4096*64 u64 = 2 MB
    float* Wh1  = (float*)(packA + (size_t)NN * 64);  // 1 MB
    float* Wh2  = Wh1 + (size_t)NN * FF;              // 1 MB
    float* s11  = Wh2 + (size_t)NN * FF;
    float* s12  = s11 + NN;
    float* s21  = s12 + NN;
    float* s22  = s21 + NN;
    float* colsum = s22 + NN;                     // 128
    float* colsq  = colsum + 128;                 // 128

    hipMemsetAsync(colsum, 0, 256 * sizeof(float), stream);

    pack_kernel<<<NN, 256, 0, stream>>>(adj, packA);
    wh_kernel<<<NN, 128, 0, stream>>>(h, W1, W2, a, Wh1, Wh2, s11, s12, s21, s22);
    attn_kernel<<<NN, 256, 0, stream>>>(packA, Wh1, Wh2, s11, s12, s21, s22, hp);
    stats_kernel<<<256, 256, 0, stream>>>(hp, colsum, colsq);
    norm_kernel<<<(NN * 128 + 255) / 256, 256, 0, stream>>>(hp, colsum, colsq, gamma, beta);
}

// Round 2
// 189.805 us; speedup vs baseline: 1.2220x; 1.2220x over previous
//
#include <hip/hip_runtime.h>
#include <hip/hip_bf16.h>

#define NN 4096
#define IN_F 512
#define HALF 256
#define FF 64
#define ALPHA 0.2f
#define EPSV 1e-5f
#define CAP2 1024

typedef unsigned long long u64;
typedef unsigned int u32;

__device__ __forceinline__ float lrelu(float x){ return x > 0.f ? x : ALPHA * x; }

// ---------------- Kernel 1: bit-pack adjacency rows ----------------
__global__ __launch_bounds__(256) void pack_kernel(const float* __restrict__ adj,
                                                   u64* __restrict__ packA) {
    int i = blockIdx.x;
    int tid = threadIdx.x;
    int wave = tid >> 6, lane = tid & 63;
    const float* row = adj + (size_t)i * NN;
    #pragma unroll
    for (int t = 0; t < NN / 256; ++t) {
        int col = t * 256 + tid;
        u64 m = __ballot(row[col] > 0.f);
        if (lane == 0) packA[(size_t)i * 64 + t * 4 + wave] = m;
    }
}

// ---------------- Kernel 2: Wh GEMV, 4 rows/block with W register reuse ----------------
__global__ __launch_bounds__(128) void wh_kernel(const float* __restrict__ h,
                                                 const float* __restrict__ W1,
                                                 const float* __restrict__ W2,
                                                 const float* __restrict__ a,
                                                 float* __restrict__ Wh1,
                                                 float* __restrict__ Wh2,
                                                 float* __restrict__ s11,
                                                 float* __restrict__ s12,
                                                 float* __restrict__ s21,
                                                 float* __restrict__ s22) {
    __shared__ float hs[4 * IN_F];   // 8 KB
    int r0 = blockIdx.x * 4;
    int tid = threadIdx.x;
    // stage 4 h-rows (2048 floats = 512 float4)
    const float4* hsrc = (const float4*)(h + (size_t)r0 * IN_F);
    float4* hdst = (float4*)hs;
    #pragma unroll
    for (int t = 0; t < 4; ++t) hdst[tid + 128 * t] = hsrc[tid + 128 * t];
    __syncthreads();

    int wave = tid >> 6, f = tid & 63;
    const float* W = wave ? W2 : W1;
    const float* hw = hs + wave * HALF;
    float acc0 = 0.f, acc1 = 0.f, acc2 = 0.f, acc3 = 0.f;
    #pragma unroll 4
    for (int k = 0; k < HALF; ++k) {
        float w = W[k * FF + f];
        acc0 += hw[k] * w;
        acc1 += hw[IN_F + k] * w;
        acc2 += hw[2 * IN_F + k] * w;
        acc3 += hw[3 * IN_F + k] * w;
    }
    float* Wh = wave ? Wh2 : Wh1;
    Wh[(size_t)(r0 + 0) * FF + f] = acc0;
    Wh[(size_t)(r0 + 1) * FF + f] = acc1;
    Wh[(size_t)(r0 + 2) * FF + f] = acc2;
    Wh[(size_t)(r0 + 3) * FF + f] = acc3;

    float a1 = a[f], a2 = a[64 + f];
    #pragma unroll
    for (int r = 0; r < 4; ++r) {
        float acc = (r == 0) ? acc0 : (r == 1) ? acc1 : (r == 2) ? acc2 : acc3;
        float v1 = acc * a1, v2 = acc * a2;
        #pragma unroll
        for (int off = 32; off; off >>= 1) {
            v1 += __shfl_down(v1, off, 64);
            v2 += __shfl_down(v2, off, 64);
        }
        if (f == 0) {
            if (wave == 0) { s11[r0 + r] = v1; s12[r0 + r] = v2; }
            else           { s21[r0 + r] = v1; s22[r0 + r] = v2; }
        }
    }
}

// ---------------- softmax + float4 gather over a compacted list ----------------
__device__ __forceinline__ void softmax_gather(int cnt, const int* __restrict__ nbr,
                                               float* __restrict__ ev,
                                               const float* __restrict__ Wh,
                                               float* __restrict__ outp,
                                               int tid, float* red, float* partial) {
    int wave = tid >> 6, lane = tid & 63;
    float Z;
    if (cnt > 0) {
        float m = -3.4e38f;
        for (int n = tid; n < cnt; n += 256) m = fmaxf(m, ev[n]);
        #pragma unroll
        for (int off = 32; off; off >>= 1) m = fmaxf(m, __shfl_down(m, off, 64));
        if (lane == 0) red[wave] = m;
        __syncthreads();
        m = fmaxf(fmaxf(red[0], red[1]), fmaxf(red[2], red[3]));
        float s = 0.f;
        for (int n = tid; n < cnt; n += 256) {
            float p = __expf(ev[n] - m);
            ev[n] = p;
            s += p;
        }
        #pragma unroll
        for (int off = 32; off; off >>= 1) s += __shfl_down(s, off, 64);
        __syncthreads();                 // red reuse + ev writes visible
        if (lane == 0) red[wave] = s;
        __syncthreads();
        Z = red[0] + red[1] + red[2] + red[3];
    } else {
        Z = (float)NN;
    }
    // gather: 16 row-groups x 16 lanes, float4 columns
    int g = tid >> 4;
    int fq = (tid & 15) << 2;
    float ax = 0.f, ay = 0.f, az = 0.f, aw = 0.f;
    if (cnt > 0) {
        for (int n = g; n < cnt; n += 16) {
            float w = ev[n];
            const float4 v = *reinterpret_cast<const float4*>(&Wh[(size_t)nbr[n] * FF + fq]);
            ax += w * v.x; ay += w * v.y; az += w * v.z; aw += w * v.w;
        }
    } else {
        for (int n = g; n < NN; n += 16) {
            const float4 v = *reinterpret_cast<const float4*>(&Wh[(size_t)n * FF + fq]);
            ax += v.x; ay += v.y; az += v.z; aw += v.w;
        }
    }
    float4 accv = make_float4(ax, ay, az, aw);
    *reinterpret_cast<float4*>(&partial[tid << 2]) = accv;   // = partial[g*64 + fq]
    __syncthreads();
    if (tid < 64) {
        float s = 0.f;
        #pragma unroll
        for (int g2 = 0; g2 < 16; ++g2) s += partial[g2 * 64 + tid];
        outp[tid] = s / Z;
    }
}

// wave-0 list build from 64 packed words: popcount + prefix scan, no atomics.
// Returns count via *pcnt (LDS). ev filled with lrelu(si + sj[j]) when sj != nullptr.
__device__ __forceinline__ void build_list(u64 bits, int lane, int* __restrict__ nbr,
                                           float* __restrict__ ev, float si,
                                           const float* __restrict__ sj, int* pcnt) {
    int pc = __popcll(bits);
    int scan = pc;
    #pragma unroll
    for (int off = 1; off < 64; off <<= 1) {
        int v = __shfl_up(scan, off, 64);
        if (lane >= off) scan += v;
    }
    int pos = scan - pc;
    while (bits) {
        int b = __builtin_ctzll(bits);
        bits &= bits - 1;
        int j = (lane << 6) | b;
        if (pos < CAP2) {
            nbr[pos] = j;
            if (sj) ev[pos] = lrelu(si + sj[j]);
        }
        ++pos;
    }
    if (lane == 63) *pcnt = scan;
}

// ---------------- Kernel 3: fused attention; blocks [0,NN)=hop1, [NN,2NN)=hop2 ----------------
__global__ __launch_bounds__(256) void attn_kernel(const u64* __restrict__ packA,
                                                   const float* __restrict__ Wh1,
                                                   const float* __restrict__ Wh2,
                                                   const float* __restrict__ s11,
                                                   const float* __restrict__ s12,
                                                   const float* __restrict__ s21,
                                                   const float* __restrict__ s22,
                                                   float* __restrict__ hp) {
    __shared__ int   nbr[CAP2];
    __shared__ float ev[CAP2];
    __shared__ u64   maskw[4 * 64];
    __shared__ float red[4];
    __shared__ float partial[1024];
    __shared__ int   scnt;

    int bid = blockIdx.x;
    int tid = threadIdx.x;
    int wave = tid >> 6, lane = tid & 63;
    bool hop2 = bid >= NN;
    int i = hop2 ? bid - NN : bid;

    if (!hop2) {
        if (wave == 0)
            build_list(packA[(size_t)i * 64 + lane], lane, nbr, ev, s11[i], s12, &scnt);
        __syncthreads();
        int c1 = min(scnt, CAP2);
        softmax_gather(c1, nbr, ev, Wh1, hp + (size_t)i * 128, tid, red, partial);
    } else {
        // hop-1 indices only
        if (wave == 0)
            build_list(packA[(size_t)i * 64 + lane], lane, nbr, ev, 0.f, nullptr, &scnt);
        __syncthreads();
        int c1 = min(scnt, CAP2);
        // 2-hop mask: register-OR across this wave's share of neighbor rows
        u64 m = 0;
        for (int n = wave; n < c1; n += 4)
            m |= packA[(size_t)nbr[n] * 64 + lane];
        maskw[wave * 64 + lane] = m;
        __syncthreads();
        if (wave == 0) {
            u64 word = maskw[lane] | maskw[64 + lane] | maskw[128 + lane] | maskw[192 + lane];
            if (lane == (i >> 6)) word &= ~(1ull << (i & 63));   // zero diag of adj2
            build_list(word, lane, nbr, ev, s21[i], s22, &scnt);
        }
        __syncthreads();
        int c2 = min(scnt, CAP2);
        softmax_gather(c2, nbr, ev, Wh2, hp + (size_t)i * 128 + 64, tid, red, partial);
    }
}

// ---------------- Kernel 4: column sums (float4) ----------------
__global__ __launch_bounds__(256) void stats_kernel(const float* __restrict__ hp,
                                                    float* __restrict__ colsum,
                                                    float* __restrict__ colsq) {
    __shared__ float ls[128], lq[128];
    int tid = threadIdx.x;
    if (tid < 128) { ls[tid] = 0.f; lq[tid] = 0.f; }
    __syncthreads();
    float s0 = 0, s1 = 0, s2 = 0, s3 = 0, q0 = 0, q1 = 0, q2 = 0, q3 = 0;
    const float4* hp4 = (const float4*)hp;
    for (size_t idx = (size_t)blockIdx.x * 256 + tid; idx < (size_t)NN * 32;
         idx += (size_t)gridDim.x * 256) {
        float4 v = hp4[idx];
        s0 += v.x; q0 += v.x * v.x;
        s1 += v.y; q1 += v.y * v.y;
        s2 += v.z; q2 += v.z * v.z;
        s3 += v.w; q3 += v.w * v.w;
    }
    int cb = (tid & 31) << 2;    // (idx*4)%128 == (tid*4)%128, strides are multiples of 128
    atomicAdd(&ls[cb + 0], s0); atomicAdd(&lq[cb + 0], q0);
    atomicAdd(&ls[cb + 1], s1); atomicAdd(&lq[cb + 1], q1);
    atomicAdd(&ls[cb + 2], s2); atomicAdd(&lq[cb + 2], q2);
    atomicAdd(&ls[cb + 3], s3); atomicAdd(&lq[cb + 3], q3);
    __syncthreads();
    if (tid < 128) {
        atomicAdd(&colsum[tid], ls[tid]);
        atomicAdd(&colsq[tid], lq[tid]);
    }
}

// ---------------- Kernel 5: batchnorm + lrelu, float4 in place ----------------
__global__ __launch_bounds__(256) void norm_kernel(float* __restrict__ hp,
                                                   const float* __restrict__ colsum,
                                                   const float* __restrict__ colsq,
                                                   const float* __restrict__ gamma,
                                                   const float* __restrict__ beta) {
    size_t idx = (size_t)blockIdx.x * 256 + threadIdx.x;
    if (idx >= (size_t)NN * 32) return;
    int cb = (int)((idx << 2) & 127);
    float4 v = ((const float4*)hp)[idx];
    float r[4] = {v.x, v.y, v.z, v.w};
    #pragma unroll
    for (int t = 0; t < 4; ++t) {
        int c = cb + t;
        float mean = colsum[c] * (1.f / NN);
        float var = colsq[c] * (1.f / NN) - mean * mean;
        float inv = rsqrtf(var + EPSV);
        r[t] = lrelu((r[t] - mean) * inv * gamma[c] + beta[c]);
    }
    ((float4*)hp)[idx] = make_float4(r[0], r[1], r[2], r[3]);
}

extern "C" void kernel_launch(void* const* d_in, const int* in_sizes, int n_in,
                              void* d_out, int out_size, void* d_ws, size_t ws_size,
                              hipStream_t stream) {
    const float* h     = (const float*)d_in[0];
    const float* adj   = (const float*)d_in[1];
    const float* W1    = (const float*)d_in[2];
    const float* W2    = (const float*)d_in[3];
    const float* a     = (const float*)d_in[4];
    const float* gamma = (const float*)d_in[5];
    const float* beta  = (const float*)d_in[6];
    float* hp = (float*)d_out;   // [4096, 128]

    u64* packA  = (u64*)d_ws;                         // 2 MB
    float* Wh1  = (float*)(packA + (size_t)NN * 64);  // 1 MB
    float* Wh2  = Wh1 + (size_t)NN * FF;              // 1 MB
    float* s11  = Wh2 + (size_t)NN * FF;
    float* s12  = s11 + NN;
    float* s21  = s12 + NN;
    float* s22  = s21 + NN;
    float* colsum = s22 + NN;                         // 128
    float* colsq  = colsum + 128;                     // 128

    hipMemsetAsync(colsum, 0, 256 * sizeof(float), stream);

    pack_kernel<<<NN, 256, 0, stream>>>(adj, packA);
    wh_kernel<<<NN / 4, 128, 0, stream>>>(h, W1, W2, a, Wh1, Wh2, s11, s12, s21, s22);
    attn_kernel<<<2 * NN, 256, 0, stream>>>(packA, Wh1, Wh2, s11, s12, s21, s22, hp);
    stats_kernel<<<256, 256, 0, stream>>>(hp, colsum, colsq);
    norm_kernel<<<(NN * 32 + 255) / 256, 256, 0, stream>>>(hp, colsum, colsq, gamma, beta);
}